// Round 1
// baseline (1994.740 us; speedup 1.0000x reference)
//
#include <hip/hip_runtime.h>
#include <cstdint>

// Problem constants: B=2, Q=512, K=512, T=256 (all fp32)

#define FMA16()                                                                 \
  c[0][0] += a.x*w.x; c[0][1] += a.x*w.y; c[0][2] += a.x*w.z; c[0][3] += a.x*w.w; \
  c[1][0] += a.y*w.x; c[1][1] += a.y*w.y; c[1][2] += a.y*w.z; c[1][3] += a.y*w.w; \
  c[2][0] += a.z*w.x; c[2][1] += a.z*w.y; c[2][2] += a.z*w.z; c[2][3] += a.z*w.w; \
  c[3][0] += a.w*w.x; c[3][1] += a.w*w.y; c[3][2] += a.w*w.z; c[3][3] += a.w*w.w;

// Transpose the 5 weight matrices W[u][t] -> WT[t][u] (each 256x256).
__global__ __launch_bounds__(256) void transpose5(
    const float* __restrict__ W0, const float* __restrict__ W1,
    const float* __restrict__ W2, const float* __restrict__ W3,
    const float* __restrict__ W4, float* __restrict__ WT)
{
  const int u = blockIdx.x;     // 0..255
  const int m = blockIdx.y;     // which matrix
  const float* W = (m == 0) ? W0 : (m == 1) ? W1 : (m == 2) ? W2 : (m == 3) ? W3 : W4;
  const int t = threadIdx.x;    // 0..255  (coalesced read)
  WT[(size_t)m * 65536 + (size_t)t * 256 + u] = W[u * 256 + t];
}

// Generic C[m,u] = sum_t X[m,t] * WT[t,u].  M=1024, N=256, K=256.
// 64x64 tile, 256 threads, 4x4 per thread.
__global__ __launch_bounds__(256) void gemm_tn(
    const float* __restrict__ X, const float* __restrict__ WT, float* __restrict__ C)
{
  __shared__ __align__(16) float As[16][68];
  __shared__ __align__(16) float Ws[16][64];
  const int tid = threadIdx.x;
  const int tx4 = (tid & 15) * 4;
  const int ty4 = (tid >> 4) * 4;
  const int m0 = blockIdx.x * 64, u0 = blockIdx.y * 64;
  const int lmi = tid >> 2, lc4 = (tid & 3) * 4;     // A-stage mapping
  const int lr  = tid >> 4, lu4 = (tid & 15) * 4;    // W-stage mapping
  float c[4][4] = {};
#pragma unroll 1
  for (int t0 = 0; t0 < 256; t0 += 16) {
    const float4 xa = *(const float4*)&X[(size_t)(m0 + lmi) * 256 + t0 + lc4];
    const float4 wb = *(const float4*)&WT[(size_t)(t0 + lr) * 256 + u0 + lu4];
    __syncthreads();
    As[lc4 + 0][lmi] = xa.x; As[lc4 + 1][lmi] = xa.y;
    As[lc4 + 2][lmi] = xa.z; As[lc4 + 3][lmi] = xa.w;
    *(float4*)&Ws[lr][lu4] = wb;
    __syncthreads();
#pragma unroll
    for (int t = 0; t < 16; ++t) {
      const float4 a = *(const float4*)&As[t][ty4];
      const float4 w = *(const float4*)&Ws[t][tx4];
      FMA16();
    }
  }
#pragma unroll
  for (int i = 0; i < 4; ++i) {
    *(float4*)&C[(size_t)(m0 + ty4 + i) * 256 + u0 + tx4] =
        make_float4(c[i][0], c[i][1], c[i][2], c[i][3]);
  }
}

// Kernel A: per (b,k,u-chunk of 64): stream logits over all q (8 tiles of 64),
// online max m[u] and denominator den[u] = sum_q |x*exp(x-m)|.
// Writes m_g[b,k,u] and sfac[b,k,u] = vproj[b,k,u] / (den+1).
__global__ __launch_bounds__(256) void kernelA(
    const float* __restrict__ qproj, const float* __restrict__ kproj,
    const float* __restrict__ vproj, const float* __restrict__ WalT,
    float* __restrict__ m_g, float* __restrict__ sfac)
{
  __shared__ __align__(16) float W2[256][64];   // WalT tile scaled by kp (resident)
  __shared__ __align__(16) float As[16][68];    // qproj chunk, [t][q]
  __shared__ __align__(16) float red[16][68];   // cross-thread reduction
  __shared__ float kp[256];
  __shared__ float mcur[64];
  __shared__ float dcur[64];

  const int k = blockIdx.x, uc = blockIdx.y, b = blockIdx.z;
  const int u0 = uc * 64;
  const int tid = threadIdx.x;
  const int tx4 = (tid & 15) * 4;
  const int ty4 = (tid >> 4) * 4;
  const int lmi = tid >> 2, lc4 = (tid & 3) * 4;
  const int lr  = tid >> 4, lu4 = (tid & 15) * 4;

  const size_t krow = (size_t)(b * 512 + k) * 256;
  kp[tid] = kproj[krow + tid];
  if (tid < 64) { mcur[tid] = -1e30f; dcur[tid] = 0.0f; }
  __syncthreads();

  // Stage W2[t][u] = WalT[t][u0+u] * kp[t], full 256 x 64 (64 KB)
#pragma unroll
  for (int rr = 0; rr < 16; ++rr) {
    const int r = rr * 16 + lr;
    float4 w = *(const float4*)&WalT[(size_t)r * 256 + u0 + lu4];
    const float s = kp[r];
    w.x *= s; w.y *= s; w.z *= s; w.w *= s;
    *(float4*)&W2[r][lu4] = w;
  }
  __syncthreads();

  const float* qbase = qproj + (size_t)b * 512 * 256;

#pragma unroll 1
  for (int qt = 0; qt < 8; ++qt) {
    const int q0 = qt * 64;
    float c[4][4] = {};
#pragma unroll 1
    for (int t0 = 0; t0 < 256; t0 += 16) {
      const float4 xa = *(const float4*)&qbase[(size_t)(q0 + lmi) * 256 + t0 + lc4];
      __syncthreads();
      As[lc4 + 0][lmi] = xa.x; As[lc4 + 1][lmi] = xa.y;
      As[lc4 + 2][lmi] = xa.z; As[lc4 + 3][lmi] = xa.w;
      __syncthreads();
#pragma unroll
      for (int t = 0; t < 16; ++t) {
        const float4 a = *(const float4*)&As[t][ty4];
        const float4 w = *(const float4*)&W2[t0 + t][tx4];
        FMA16();
      }
    }
    // ---- online swishmax update over this q-tile ----
    // phase 1: per-u tile max
    float cm[4];
#pragma unroll
    for (int j = 0; j < 4; ++j)
      cm[j] = fmaxf(fmaxf(c[0][j], c[1][j]), fmaxf(c[2][j], c[3][j]));
    __syncthreads();  // prior red readers done
    *(float4*)&red[tid >> 4][tx4] = make_float4(cm[0], cm[1], cm[2], cm[3]);
    __syncthreads();
    if (tid < 64) {
      float tm = red[0][tid];
#pragma unroll
      for (int r = 1; r < 16; ++r) tm = fmaxf(tm, red[r][tid]);
      const float mold = mcur[tid];
      const float mnew = fmaxf(mold, tm);
      dcur[tid] *= __expf(mold - mnew);   // rescale old sum; exp(-inf)=0 on first tile
      mcur[tid] = mnew;
    }
    __syncthreads();
    // phase 2: per-u partial sum of |x * exp(x - m)|
    float sj[4];
#pragma unroll
    for (int j = 0; j < 4; ++j) {
      const float mj = mcur[tx4 + j];
      float s = 0.0f;
#pragma unroll
      for (int i = 0; i < 4; ++i)
        s += fabsf(c[i][j] * __expf(c[i][j] - mj));
      sj[j] = s;
    }
    *(float4*)&red[tid >> 4][tx4] = make_float4(sj[0], sj[1], sj[2], sj[3]);
    __syncthreads();
    if (tid < 64) {
      float s = 0.0f;
#pragma unroll
      for (int r = 0; r < 16; ++r) s += red[r][tid];
      dcur[tid] += s;
    }
    __syncthreads();
  }

  if (tid < 64) {
    const size_t o = krow + u0 + tid;
    m_g[o] = mcur[tid];
    sfac[o] = vproj[o] / (dcur[tid] + 1.0f);
  }
}

// Kernel B: per (b, q-tile 64, u-chunk 64, k-seg of 32): recompute logits per k,
// acc[q,u] += sfac[b,k,u] * x * exp(x - m[b,k,u]); atomically add into vsum.
__global__ __launch_bounds__(256) void kernelB(
    const float* __restrict__ qproj, const float* __restrict__ kproj,
    const float* __restrict__ WalT, const float* __restrict__ m_g,
    const float* __restrict__ sfac, float* __restrict__ vsum)
{
  __shared__ __align__(16) float As[256][68];   // qproj tile [t][q], resident (68 KB)
  __shared__ __align__(16) float Ws[16][64];    // WalT chunk scaled by kp
  __shared__ float kp[256];

  const int qt = blockIdx.x, uc = blockIdx.y;
  const int b = blockIdx.z >> 4, kseg = blockIdx.z & 15;
  const int q0 = qt * 64, u0 = uc * 64, k0 = kseg * 32;
  const int tid = threadIdx.x;
  const int tx4 = (tid & 15) * 4;
  const int ty4 = (tid >> 4) * 4;
  const int lmi = tid >> 2, lc4 = (tid & 3) * 4;
  const int lr  = tid >> 4, lu4 = (tid & 15) * 4;

  // Stage qproj tile [64 q][256 t] -> As[t][q], once per block.
  const float* qbase = qproj + (size_t)(b * 512 + q0) * 256;
#pragma unroll 1
  for (int rr = 0; rr < 16; ++rr) {
    const int t0 = rr * 16 + lc4;
    const float4 xa = *(const float4*)&qbase[(size_t)lmi * 256 + t0];
    As[t0 + 0][lmi] = xa.x; As[t0 + 1][lmi] = xa.y;
    As[t0 + 2][lmi] = xa.z; As[t0 + 3][lmi] = xa.w;
  }

  float acc[4][4] = {};

#pragma unroll 1
  for (int k = k0; k < k0 + 32; ++k) {
    const size_t krow = (size_t)(b * 512 + k) * 256;
    __syncthreads();               // prev iter done with kp/Ws (and As staged, 1st iter)
    kp[tid] = kproj[krow + tid];
    __syncthreads();
    const float4 m4 = *(const float4*)&m_g[krow + u0 + tx4];
    const float4 s4 = *(const float4*)&sfac[krow + u0 + tx4];
    float c[4][4] = {};
#pragma unroll 1
    for (int t0 = 0; t0 < 256; t0 += 16) {
      float4 wb = *(const float4*)&WalT[(size_t)(t0 + lr) * 256 + u0 + lu4];
      const float s = kp[t0 + lr];
      __syncthreads();             // prev chunk readers done with Ws
      wb.x *= s; wb.y *= s; wb.z *= s; wb.w *= s;
      *(float4*)&Ws[lr][lu4] = wb;
      __syncthreads();
#pragma unroll
      for (int t = 0; t < 16; ++t) {
        const float4 a = *(const float4*)&As[t0 + t][ty4];
        const float4 w = *(const float4*)&Ws[t][tx4];
        FMA16();
      }
    }
    // epilogue: weighted accumulate
    const float mj[4] = { m4.x, m4.y, m4.z, m4.w };
    const float sf[4] = { s4.x, s4.y, s4.z, s4.w };
#pragma unroll
    for (int j = 0; j < 4; ++j)
#pragma unroll
      for (int i = 0; i < 4; ++i) {
        const float x = c[i][j];
        acc[i][j] += sf[j] * x * __expf(x - mj[j]);
      }
  }

#pragma unroll
  for (int i = 0; i < 4; ++i)
#pragma unroll
    for (int j = 0; j < 4; ++j)
      atomicAdd(&vsum[(size_t)(b * 512 + q0 + ty4 + i) * 256 + u0 + tx4 + j], acc[i][j]);
}

extern "C" void kernel_launch(void* const* d_in, const int* in_sizes, int n_in,
                              void* d_out, int out_size, void* d_ws, size_t ws_size,
                              hipStream_t stream) {
  const float* query = (const float*)d_in[0];
  const float* key   = (const float*)d_in[1];
  const float* value = (const float*)d_in[2];
  const float* Wk    = (const float*)d_in[3];
  const float* Wq    = (const float*)d_in[4];
  const float* Wva   = (const float*)d_in[5];
  const float* Wal   = (const float*)d_in[6];
  const float* Wvo   = (const float*)d_in[7];
  float* ws = (float*)d_ws;

  float* WT    = ws;                     // 5 * 65536  (order: WkT, WqT, WvaT, WalT, WvoT)
  float* WkT   = WT;
  float* WqT   = WT + 65536;
  float* WvaT  = WT + 2 * 65536;
  float* WalT  = WT + 3 * 65536;
  float* WvoT  = WT + 4 * 65536;
  float* qproj = ws + 327680;            // 262144 each below
  float* kproj = qproj + 262144;
  float* vproj = kproj + 262144;
  float* m_g   = vproj + 262144;
  float* sfac  = m_g + 262144;
  float* vsum  = sfac + 262144;
  float* out   = (float*)d_out;

  hipMemsetAsync(vsum, 0, 262144 * sizeof(float), stream);

  transpose5<<<dim3(256, 5), 256, 0, stream>>>(Wk, Wq, Wva, Wal, Wvo, WT);

  gemm_tn<<<dim3(16, 4), 256, 0, stream>>>(query, WqT, qproj);
  gemm_tn<<<dim3(16, 4), 256, 0, stream>>>(key,   WkT, kproj);
  gemm_tn<<<dim3(16, 4), 256, 0, stream>>>(value, WvaT, vproj);

  kernelA<<<dim3(512, 4, 2), 256, 0, stream>>>(qproj, kproj, vproj, WalT, m_g, sfac);
  kernelB<<<dim3(8, 4, 32),  256, 0, stream>>>(qproj, kproj, WalT, m_g, sfac, vsum);

  gemm_tn<<<dim3(16, 4), 256, 0, stream>>>(vsum, WvoT, out);
}

// Round 2
// 465.037 us; speedup vs baseline: 4.2894x; 4.2894x over previous
//
#include <hip/hip_runtime.h>
#include <cstdint>

// B=2, Q=512, K=512, T=256 (fp32 in/out). Heavy logits GEMMs on bf16 MFMA.

typedef short bf16x8 __attribute__((ext_vector_type(8)));   // 8 bf16 = 4 VGPR (MFMA A/B frag)
typedef float f32x4  __attribute__((ext_vector_type(4)));   // MFMA C/D frag

__device__ inline float bf2f(short s) {
  return __uint_as_float(((unsigned)(unsigned short)s) << 16);
}
// round-to-nearest (ties up) f32->bf16, packed pair: low short = lo, high short = hi
__device__ inline unsigned packrn(float lo, float hi) {
  return __builtin_amdgcn_perm(__float_as_uint(hi) + 0x8000u,
                               __float_as_uint(lo) + 0x8000u, 0x07060302u);
}

union U16B { unsigned u[4]; bf16x8 v; };

#define FMA16()                                                                 \
  c[0][0] += a.x*w.x; c[0][1] += a.x*w.y; c[0][2] += a.x*w.z; c[0][3] += a.x*w.w; \
  c[1][0] += a.y*w.x; c[1][1] += a.y*w.y; c[1][2] += a.y*w.z; c[1][3] += a.y*w.w; \
  c[2][0] += a.z*w.x; c[2][1] += a.z*w.y; c[2][2] += a.z*w.z; c[2][3] += a.z*w.w; \
  c[3][0] += a.w*w.x; c[3][1] += a.w*w.y; c[3][2] += a.w*w.z; c[3][3] += a.w*w.w;

// Transpose the 5 weight matrices W[u][t] -> WT[t][u] (each 256x256).
__global__ __launch_bounds__(256) void transpose5(
    const float* __restrict__ W0, const float* __restrict__ W1,
    const float* __restrict__ W2, const float* __restrict__ W3,
    const float* __restrict__ W4, float* __restrict__ WT)
{
  const int u = blockIdx.x;
  const int m = blockIdx.y;
  const float* W = (m == 0) ? W0 : (m == 1) ? W1 : (m == 2) ? W2 : (m == 3) ? W3 : W4;
  const int t = threadIdx.x;
  WT[(size_t)m * 65536 + (size_t)t * 256 + u] = W[u * 256 + t];
}

// f32 -> bf16 copy (4 el/thread)
__global__ __launch_bounds__(256) void cvt_bf16x4(
    const float* __restrict__ src, short* __restrict__ dst)
{
  const int i = (blockIdx.x * 256 + threadIdx.x) * 4;
  const float4 v = *(const float4*)&src[i];
  uint2 s; s.x = packrn(v.x, v.y); s.y = packrn(v.z, v.w);
  *(uint2*)&dst[i] = s;
}

// C[m,u] = sum_t X[m,t] * WT[t,u].  M=1024, N=256, K=256. fp32 VALU (small).
// BF16OUT=1 writes bf16 (short) output instead of f32.
template<int BF16OUT>
__global__ __launch_bounds__(256) void gemm_tn_t(
    const float* __restrict__ X, const float* __restrict__ WT, void* __restrict__ Cout)
{
  __shared__ __align__(16) float As[16][68];
  __shared__ __align__(16) float Ws[16][64];
  const int tid = threadIdx.x;
  const int tx4 = (tid & 15) * 4;
  const int ty4 = (tid >> 4) * 4;
  const int m0 = blockIdx.x * 64, u0 = blockIdx.y * 64;
  const int lmi = tid >> 2, lc4 = (tid & 3) * 4;
  const int lr  = tid >> 4, lu4 = (tid & 15) * 4;
  float c[4][4] = {};
#pragma unroll 1
  for (int t0 = 0; t0 < 256; t0 += 16) {
    const float4 xa = *(const float4*)&X[(size_t)(m0 + lmi) * 256 + t0 + lc4];
    const float4 wb = *(const float4*)&WT[(size_t)(t0 + lr) * 256 + u0 + lu4];
    __syncthreads();
    As[lc4 + 0][lmi] = xa.x; As[lc4 + 1][lmi] = xa.y;
    As[lc4 + 2][lmi] = xa.z; As[lc4 + 3][lmi] = xa.w;
    *(float4*)&Ws[lr][lu4] = wb;
    __syncthreads();
#pragma unroll
    for (int t = 0; t < 16; ++t) {
      const float4 a = *(const float4*)&As[t][ty4];
      const float4 w = *(const float4*)&Ws[t][tx4];
      FMA16();
    }
  }
  if (BF16OUT) {
    short* C = (short*)Cout;
#pragma unroll
    for (int i = 0; i < 4; ++i) {
      uint2 s; s.x = packrn(c[i][0], c[i][1]); s.y = packrn(c[i][2], c[i][3]);
      *(uint2*)&C[(size_t)(m0 + ty4 + i) * 256 + u0 + tx4] = s;
    }
  } else {
    float* C = (float*)Cout;
#pragma unroll
    for (int i = 0; i < 4; ++i)
      *(float4*)&C[(size_t)(m0 + ty4 + i) * 256 + u0 + tx4] =
          make_float4(c[i][0], c[i][1], c[i][2], c[i][3]);
  }
}

// ---------------------------------------------------------------------------
// Kernel A (MFMA): block = (k, uc(64 u's), b). Computes, for its (k, u-tile):
// online max over all 512 q and den = sum_q |x*exp(x-m)| of
//   logits[q,u] = sum_t qp[q,t] * (kp[k,t]*Wal[u,t])
// Writes m_g[b,k,u], sfac[b,k,u] = vproj/(den+1).
// Wave tiling: qh=w>>1 (q 32-half of 64-chunk), uh=w&1 (u 32-half of tile).
// ---------------------------------------------------------------------------
__global__ __launch_bounds__(256, 2) void kernelA(
    const short* __restrict__ qp_b, const float* __restrict__ kproj,
    const float* __restrict__ vproj, const short* __restrict__ Walb,
    float* __restrict__ m_g, float* __restrict__ sfac)
{
  __shared__ short W2s[64 * 264];     // [u][t] bf16, padded rows (2-way-free frag reads)
  __shared__ short Aqs[64 * 264];     // [q][t] bf16, padded
  __shared__ float kpS[256];
  __shared__ float mS[4][34];
  __shared__ float dS[4][34];

  const int k = blockIdx.x, uc = blockIdx.y, b = blockIdx.z;
  const int u0 = uc * 64;
  const int tid = threadIdx.x;
  const int lane = tid & 63, w = tid >> 6;
  const int qh = w >> 1, uh = w & 1;
  const int l15 = lane & 15, l4 = lane >> 4;

  const long krow = (long)(b * 512 + k) * 256;
  kpS[tid] = kproj[krow + tid];
  __syncthreads();

  // Build W2s[u][t] = rn_bf16( f32(Walb[u0+u][t]) * kp[t] )  (identical math to kernelB)
#pragma unroll
  for (int i = 0; i < 8; ++i) {
    const int flat = tid + 256 * i;          // 8-element chunks
    const int r = flat >> 5, c8 = flat & 31;
    const bf16x8 wv = *(const bf16x8*)&Walb[(size_t)(u0 + r) * 256 + c8 * 8];
    const f32x4 k0 = *(const f32x4*)&kpS[c8 * 8];
    const f32x4 k1 = *(const f32x4*)&kpS[c8 * 8 + 4];
    uint4 st;
    st.x = packrn(bf2f(wv[0]) * k0[0], bf2f(wv[1]) * k0[1]);
    st.y = packrn(bf2f(wv[2]) * k0[2], bf2f(wv[3]) * k0[3]);
    st.z = packrn(bf2f(wv[4]) * k1[0], bf2f(wv[5]) * k1[1]);
    st.w = packrn(bf2f(wv[6]) * k1[2], bf2f(wv[7]) * k1[3]);
    *(uint4*)&W2s[r * 264 + c8 * 8] = st;
  }
  __syncthreads();

  // Preload B-frags (W2 is fixed for whole block): wf[us][ks]
  bf16x8 wf[2][8];
#pragma unroll
  for (int us = 0; us < 2; ++us)
#pragma unroll
    for (int ks = 0; ks < 8; ++ks)
      wf[us][ks] = *(const bf16x8*)&W2s[(uh * 32 + us * 16 + l15) * 264 + ks * 32 + l4 * 8];

  float mrun[2] = {-3e38f, -3e38f};
  float drun[2] = {0.f, 0.f};
  const f32x4 z4 = {0.f, 0.f, 0.f, 0.f};

#pragma unroll 1
  for (int qt = 0; qt < 8; ++qt) {
    __syncthreads();   // prior chunk's A-frag reads complete
    const short* src = &qp_b[(size_t)(b * 512 + qt * 64) * 256];
#pragma unroll
    for (int i = 0; i < 8; ++i) {
      const int flat = tid + 256 * i;
      const int r = flat >> 5, c8 = flat & 31;
      *(uint4*)&Aqs[r * 264 + c8 * 8] = *(const uint4*)&src[r * 256 + c8 * 8];
    }
    __syncthreads();

    bf16x8 af[2][8];
#pragma unroll
    for (int qs = 0; qs < 2; ++qs)
#pragma unroll
      for (int ks = 0; ks < 8; ++ks)
        af[qs][ks] = *(const bf16x8*)&Aqs[(qh * 32 + qs * 16 + l15) * 264 + ks * 32 + l4 * 8];

    f32x4 lg[2][2] = {z4, z4, z4, z4};
#pragma unroll
    for (int ks = 0; ks < 8; ++ks)
#pragma unroll
      for (int qs = 0; qs < 2; ++qs)
#pragma unroll
        for (int us = 0; us < 2; ++us)
          lg[qs][us] = __builtin_amdgcn_mfma_f32_16x16x32_bf16(
              af[qs][ks], wf[us][ks], lg[qs][us], 0, 0, 0);

    // online swishmax state update (per u column = lane&15 of each us)
#pragma unroll
    for (int us = 0; us < 2; ++us) {
      float tm = lg[0][us][0];
#pragma unroll
      for (int qs = 0; qs < 2; ++qs)
#pragma unroll
        for (int i = 0; i < 4; ++i) tm = fmaxf(tm, lg[qs][us][i]);
      tm = fmaxf(tm, __shfl_xor(tm, 16));
      tm = fmaxf(tm, __shfl_xor(tm, 32));
      const float mnew = fmaxf(mrun[us], tm);
      float s = 0.f;
#pragma unroll
      for (int qs = 0; qs < 2; ++qs)
#pragma unroll
        for (int i = 0; i < 4; ++i) {
          const float x = lg[qs][us][i];
          s += fabsf(x) * __expf(x - mnew);
        }
      s += __shfl_xor(s, 16);
      s += __shfl_xor(s, 32);
      drun[us] = drun[us] * __expf(mrun[us] - mnew) + s;
      mrun[us] = mnew;
    }
  }

  // cross-wave merge over q-halves (partner = w^2), then write m_g / sfac
  if (l4 == 0) {
#pragma unroll
    for (int us = 0; us < 2; ++us) {
      mS[w][us * 16 + l15] = mrun[us];
      dS[w][us * 16 + l15] = drun[us];
    }
  }
  __syncthreads();
  if (w < 2) {
#pragma unroll
    for (int us = 0; us < 2; ++us) {
      const float m2 = mS[w + 2][us * 16 + l15];
      const float d2 = dS[w + 2][us * 16 + l15];
      const float mf = fmaxf(mrun[us], m2);
      const float df = drun[us] * __expf(mrun[us] - mf) + d2 * __expf(m2 - mf);
      if (l4 == 0) {
        const long o = krow + u0 + uh * 32 + us * 16 + l15;
        m_g[o] = mf;
        sfac[o] = vproj[o] / (df + 1.0f);
      }
    }
  }
}

// ---------------------------------------------------------------------------
// Kernel B (MFMA): block = (qt(64 q), uc(64 u), b*8+kseg(64 k)). Recomputes the
// logits tile per k (B-operand = kp*Wal built in registers), accumulates
// acc[q,u] += sfac[k,u] * x * exp(x - m[k,u]); atomicAdd into vsum at end.
// No LDS in the k-loop; A/Wal frags preloaded in VGPRs.
// ---------------------------------------------------------------------------
__global__ __launch_bounds__(256, 2) void kernelB(
    const short* __restrict__ qp_b, const float* __restrict__ kproj,
    const short* __restrict__ Walb, const float* __restrict__ m_g,
    const float* __restrict__ sfac, float* __restrict__ vsum)
{
  const int qt = blockIdx.x, uc = blockIdx.y;
  const int b = blockIdx.z >> 3, kseg = blockIdx.z & 7;
  const int q0 = qt * 64, u0 = uc * 64;
  const int tid = threadIdx.x;
  const int lane = tid & 63, w = tid >> 6;
  const int qh = w >> 1, uh = w & 1;
  const int l15 = lane & 15, l4 = lane >> 4;

  bf16x8 qaf[2][8], wbf[2][8];
#pragma unroll
  for (int qs = 0; qs < 2; ++qs)
#pragma unroll
    for (int ks = 0; ks < 8; ++ks)
      qaf[qs][ks] = *(const bf16x8*)
          &qp_b[(size_t)(b * 512 + q0 + qh * 32 + qs * 16 + l15) * 256 + ks * 32 + l4 * 8];
#pragma unroll
  for (int us = 0; us < 2; ++us)
#pragma unroll
    for (int ks = 0; ks < 8; ++ks)
      wbf[us][ks] = *(const bf16x8*)
          &Walb[(size_t)(u0 + uh * 32 + us * 16 + l15) * 256 + ks * 32 + l4 * 8];

  const f32x4 z4 = {0.f, 0.f, 0.f, 0.f};
  f32x4 acc[2][2] = {z4, z4, z4, z4};

#pragma unroll 1
  for (int kk = 0; kk < 64; ++kk) {
    const int k = kseg * 64 + kk;
    const long krow = (long)(b * 512 + k) * 256;

    float mv[2], sv[2];
#pragma unroll
    for (int us = 0; us < 2; ++us) {
      const long o = krow + u0 + uh * 32 + us * 16 + l15;
      mv[us] = m_g[o];
      sv[us] = sfac[o];
    }

    f32x4 lg[2][2] = {z4, z4, z4, z4};
#pragma unroll
    for (int ks = 0; ks < 8; ++ks) {
      const f32x4 kp0 = *(const f32x4*)&kproj[krow + ks * 32 + l4 * 8];
      const f32x4 kp1 = *(const f32x4*)&kproj[krow + ks * 32 + l4 * 8 + 4];
      bf16x8 b2[2];
#pragma unroll
      for (int us = 0; us < 2; ++us) {
        const bf16x8 wv = wbf[us][ks];
        U16B t;
        t.u[0] = packrn(bf2f(wv[0]) * kp0[0], bf2f(wv[1]) * kp0[1]);
        t.u[1] = packrn(bf2f(wv[2]) * kp0[2], bf2f(wv[3]) * kp0[3]);
        t.u[2] = packrn(bf2f(wv[4]) * kp1[0], bf2f(wv[5]) * kp1[1]);
        t.u[3] = packrn(bf2f(wv[6]) * kp1[2], bf2f(wv[7]) * kp1[3]);
        b2[us] = t.v;
      }
#pragma unroll
      for (int qs = 0; qs < 2; ++qs)
#pragma unroll
        for (int us = 0; us < 2; ++us)
          lg[qs][us] = __builtin_amdgcn_mfma_f32_16x16x32_bf16(
              qaf[qs][ks], b2[us], lg[qs][us], 0, 0, 0);
    }

#pragma unroll
    for (int qs = 0; qs < 2; ++qs)
#pragma unroll
      for (int us = 0; us < 2; ++us)
#pragma unroll
        for (int i = 0; i < 4; ++i) {
          const float x = lg[qs][us][i];
          acc[qs][us][i] += sv[us] * x * __expf(x - mv[us]);
        }
  }

#pragma unroll
  for (int qs = 0; qs < 2; ++qs)
#pragma unroll
    for (int us = 0; us < 2; ++us)
#pragma unroll
      for (int i = 0; i < 4; ++i)
        atomicAdd(&vsum[(size_t)(b * 512 + q0 + qh * 32 + qs * 16 + l4 * 4 + i) * 256 +
                        u0 + uh * 32 + us * 16 + l15],
                  acc[qs][us][i]);
}

extern "C" void kernel_launch(void* const* d_in, const int* in_sizes, int n_in,
                              void* d_out, int out_size, void* d_ws, size_t ws_size,
                              hipStream_t stream) {
  const float* query = (const float*)d_in[0];
  const float* key   = (const float*)d_in[1];
  const float* value = (const float*)d_in[2];
  const float* Wk    = (const float*)d_in[3];
  const float* Wq    = (const float*)d_in[4];
  const float* Wva   = (const float*)d_in[5];
  const float* Wal   = (const float*)d_in[6];
  const float* Wvo   = (const float*)d_in[7];
  float* ws = (float*)d_ws;

  float* WT    = ws;                         // 5 * 65536
  float* WkT   = WT;
  float* WqT   = WT + 65536;
  float* WvaT  = WT + 2 * 65536;
  float* WvoT  = WT + 4 * 65536;
  float* kproj = ws + 327680;                // 262144
  float* vproj = kproj + 262144;
  float* m_g   = vproj + 262144;
  float* sfac  = m_g + 262144;
  float* vsum  = sfac + 262144;
  short* qp_b  = (short*)(vsum + 262144);    // 262144 bf16
  short* Walb  = qp_b + 262144;              // 65536 bf16
  float* out   = (float*)d_out;

  hipMemsetAsync(vsum, 0, 262144 * sizeof(float), stream);

  transpose5<<<dim3(256, 5), 256, 0, stream>>>(Wk, Wq, Wva, Wal, Wvo, WT);

  gemm_tn_t<0><<<dim3(16, 4), 256, 0, stream>>>(key,   WkT,  (void*)kproj);
  gemm_tn_t<0><<<dim3(16, 4), 256, 0, stream>>>(value, WvaT, (void*)vproj);
  gemm_tn_t<1><<<dim3(16, 4), 256, 0, stream>>>(query, WqT,  (void*)qp_b);
  cvt_bf16x4<<<dim3(64), 256, 0, stream>>>(Wal, Walb);

  kernelA<<<dim3(512, 4, 2), 256, 0, stream>>>(qp_b, kproj, vproj, Walb, m_g, sfac);
  kernelB<<<dim3(8, 4, 16), 256, 0, stream>>>(qp_b, kproj, Walb, m_g, sfac, vsum);

  gemm_tn_t<0><<<dim3(16, 4), 256, 0, stream>>>(vsum, WvoT, (void*)out);
}

// Round 4
// 303.887 us; speedup vs baseline: 6.5641x; 1.5303x over previous
//
#include <hip/hip_runtime.h>
#include <cstdint>

// B=2, Q=512, K=512, T=256 (fp32 in/out). Both heavy logits passes on bf16 MFMA,
// MFMA-bound structure: B' = kp*Wal built cooperatively in LDS once per
// (k,u-tile); A-fragments (qproj) in frag-major global layout -> registers.
// R4: restores kernelA's cross-wave (q-half) online-stat merge dropped in R3.

typedef short bf16x8 __attribute__((ext_vector_type(8)));   // 8 bf16 = 4 VGPR
typedef float f32x4  __attribute__((ext_vector_type(4)));   // MFMA C/D frag

__device__ inline float bf2f(short s) {
  return __uint_as_float(((unsigned)(unsigned short)s) << 16);
}
// f32 pair -> packed bf16 (round-half-up), low short = lo
__device__ inline unsigned packrn(float lo, float hi) {
  return __builtin_amdgcn_perm(__float_as_uint(hi) + 0x8000u,
                               __float_as_uint(lo) + 0x8000u, 0x07060302u);
}

#define FMA16()                                                                 \
  c[0][0] += a.x*w.x; c[0][1] += a.x*w.y; c[0][2] += a.x*w.z; c[0][3] += a.x*w.w; \
  c[1][0] += a.y*w.x; c[1][1] += a.y*w.y; c[1][2] += a.y*w.z; c[1][3] += a.y*w.w; \
  c[2][0] += a.z*w.x; c[2][1] += a.z*w.y; c[2][2] += a.z*w.z; c[2][3] += a.z*w.w; \
  c[3][0] += a.w*w.x; c[3][1] += a.w*w.y; c[3][2] += a.w*w.z; c[3][3] += a.w*w.w;

// Transpose the 5 weight matrices W[u][t] -> WT[t][u] (each 256x256).
__global__ __launch_bounds__(256) void transpose5(
    const float* __restrict__ W0, const float* __restrict__ W1,
    const float* __restrict__ W2, const float* __restrict__ W3,
    const float* __restrict__ W4, float* __restrict__ WT)
{
  const int u = blockIdx.x;
  const int m = blockIdx.y;
  const float* W = (m == 0) ? W0 : (m == 1) ? W1 : (m == 2) ? W2 : (m == 3) ? W3 : W4;
  const int t = threadIdx.x;
  WT[(size_t)m * 65536 + (size_t)t * 256 + u] = W[u * 256 + t];
}

// f32 -> bf16 copy (4 el/thread)
__global__ __launch_bounds__(256) void cvt_bf16x4(
    const float* __restrict__ src, short* __restrict__ dst)
{
  const int i = (blockIdx.x * 256 + threadIdx.x) * 4;
  const float4 v = *(const float4*)&src[i];
  uint2 s; s.x = packrn(v.x, v.y); s.y = packrn(v.z, v.w);
  *(uint2*)&dst[i] = s;
}

// C[m,u] = sum_t X[m,t] * WT[t,u].  M=1024, N=256, K=256. fp32 VALU (small).
// OUT=0: f32 row-major.  OUT=2: bf16 in MFMA A-frag-major layout qpF:
//   qpF[(((b*32+g)*8+ks)*64 + l4*16 + l15)*8 + j] = bf16(C[b*512+g*16+l15, ks*32+l4*8+j])
template<int OUT>
__global__ __launch_bounds__(256) void gemm_tn_t(
    const float* __restrict__ X, const float* __restrict__ WT, void* __restrict__ Cout)
{
  __shared__ __align__(16) float As[16][68];
  __shared__ __align__(16) float Ws[16][64];
  const int tid = threadIdx.x;
  const int tx4 = (tid & 15) * 4;
  const int ty4 = (tid >> 4) * 4;
  const int m0 = blockIdx.x * 64, u0 = blockIdx.y * 64;
  const int lmi = tid >> 2, lc4 = (tid & 3) * 4;
  const int lr  = tid >> 4, lu4 = (tid & 15) * 4;
  float c[4][4] = {};
#pragma unroll 1
  for (int t0 = 0; t0 < 256; t0 += 16) {
    const float4 xa = *(const float4*)&X[(size_t)(m0 + lmi) * 256 + t0 + lc4];
    const float4 wb = *(const float4*)&WT[(size_t)(t0 + lr) * 256 + u0 + lu4];
    __syncthreads();
    As[lc4 + 0][lmi] = xa.x; As[lc4 + 1][lmi] = xa.y;
    As[lc4 + 2][lmi] = xa.z; As[lc4 + 3][lmi] = xa.w;
    *(float4*)&Ws[lr][lu4] = wb;
    __syncthreads();
#pragma unroll
    for (int t = 0; t < 16; ++t) {
      const float4 a = *(const float4*)&As[t][ty4];
      const float4 w = *(const float4*)&Ws[t][tx4];
      FMA16();
    }
  }
  if (OUT == 2) {
    short* C = (short*)Cout;
    const int tbase = u0 + tx4;               // t coordinate
    const int ks = tbase >> 5, l4f = (tbase & 31) >> 3, j0 = tbase & 7;
#pragma unroll
    for (int i = 0; i < 4; ++i) {
      const int m = m0 + ty4 + i;             // global row = b*512 + q
      const int bb = m >> 9, q = m & 511;
      const int g = q >> 4, l15q = q & 15;
      const size_t idx = ((size_t)(((bb * 32 + g) * 8 + ks) * 64) + l4f * 16 + l15q) * 8 + j0;
      uint2 s; s.x = packrn(c[i][0], c[i][1]); s.y = packrn(c[i][2], c[i][3]);
      *(uint2*)&C[idx] = s;
    }
  } else {
    float* C = (float*)Cout;
#pragma unroll
    for (int i = 0; i < 4; ++i)
      *(float4*)&C[(size_t)(m0 + ty4 + i) * 256 + u0 + tx4] =
          make_float4(c[i][0], c[i][1], c[i][2], c[i][3]);
  }
}

// ---------------------------------------------------------------------------
// Kernel A (stats): block = (k, uc, b), 256 thr (4 waves: qh=w>>1, uh=w&1).
// W2[u][t] = bf16(f32(Walb)*kp) built once in LDS; B-frags -> regs; A-frags
// streamed from qpF (global, L2). Online max/den over 512 q (each wave: half),
// then cross-wave merge (partner w^2) before writing m_g / sfac.
// ---------------------------------------------------------------------------
__global__ __launch_bounds__(256, 2) void kernelA(
    const short* __restrict__ qpF, const float* __restrict__ kproj,
    const float* __restrict__ vproj, const short* __restrict__ Walb,
    float* __restrict__ m_g, float* __restrict__ sfac)
{
  __shared__ short W2s[64 * 264];    // [u][t] bf16, row pad +8
  __shared__ float mS[4][34];
  __shared__ float dS[4][34];

  const int k = blockIdx.x, uc = blockIdx.y, b = blockIdx.z;
  const int u0 = uc * 64;
  const int tid = threadIdx.x;
  const int lane = tid & 63, w = tid >> 6;
  const int qh = w >> 1, uh = w & 1;
  const int l15 = lane & 15, l4 = lane >> 4;
  const long krow = (long)(b * 512 + k) * 256;

  // cooperative W2 build
  const int c8 = tid & 31;
  const f32x4 kp0 = *(const f32x4*)&kproj[krow + c8 * 8];
  const f32x4 kp1 = *(const f32x4*)&kproj[krow + c8 * 8 + 4];
#pragma unroll
  for (int i = 0; i < 8; ++i) {
    const int r = (tid >> 5) + 8 * i;
    const bf16x8 wv = *(const bf16x8*)&Walb[(size_t)(u0 + r) * 256 + c8 * 8];
    uint4 st;
    st.x = packrn(bf2f(wv[0]) * kp0[0], bf2f(wv[1]) * kp0[1]);
    st.y = packrn(bf2f(wv[2]) * kp0[2], bf2f(wv[3]) * kp0[3]);
    st.z = packrn(bf2f(wv[4]) * kp1[0], bf2f(wv[5]) * kp1[1]);
    st.w = packrn(bf2f(wv[6]) * kp1[2], bf2f(wv[7]) * kp1[3]);
    *(uint4*)&W2s[r * 264 + c8 * 8] = st;
  }
  __syncthreads();

  // B-frags fixed for whole block
  bf16x8 wf[2][8];
#pragma unroll
  for (int us = 0; us < 2; ++us)
#pragma unroll
    for (int ks = 0; ks < 8; ++ks)
      wf[us][ks] = *(const bf16x8*)&W2s[(uh * 32 + us * 16 + l15) * 264 + ks * 32 + l4 * 8];

  float mrun[2] = {-1e30f, -1e30f};
  float drun[2] = {0.f, 0.f};
  const f32x4 z4 = {0.f, 0.f, 0.f, 0.f};
  const short* qbase = qpF + (size_t)b * 131072;

#pragma unroll 1
  for (int qt = 0; qt < 8; ++qt) {
    bf16x8 af[2][8];
#pragma unroll
    for (int qs = 0; qs < 2; ++qs) {
      const int g = qt * 4 + qh * 2 + qs;
#pragma unroll
      for (int ks = 0; ks < 8; ++ks)
        af[qs][ks] = *(const bf16x8*)&qbase[((g * 8 + ks) * 64 + lane) * 8];
    }
    f32x4 lg[2][2] = {z4, z4, z4, z4};
#pragma unroll
    for (int ks = 0; ks < 8; ++ks)
#pragma unroll
      for (int qs = 0; qs < 2; ++qs)
#pragma unroll
        for (int us = 0; us < 2; ++us)
          lg[qs][us] = __builtin_amdgcn_mfma_f32_16x16x32_bf16(
              af[qs][ks], wf[us][ks], lg[qs][us], 0, 0, 0);

#pragma unroll
    for (int us = 0; us < 2; ++us) {
      float tm = lg[0][us][0];
#pragma unroll
      for (int qs = 0; qs < 2; ++qs)
#pragma unroll
        for (int i = 0; i < 4; ++i) tm = fmaxf(tm, lg[qs][us][i]);
      tm = fmaxf(tm, __shfl_xor(tm, 16));
      tm = fmaxf(tm, __shfl_xor(tm, 32));
      const float mnew = fmaxf(mrun[us], tm);
      float s = 0.f;
#pragma unroll
      for (int qs = 0; qs < 2; ++qs)
#pragma unroll
        for (int i = 0; i < 4; ++i) {
          const float x = lg[qs][us][i];
          s += fabsf(x) * __expf(x - mnew);
        }
      s += __shfl_xor(s, 16);
      s += __shfl_xor(s, 32);
      drun[us] = drun[us] * __expf(mrun[us] - mnew) + s;
      mrun[us] = mnew;
    }
  }

  // cross-wave merge over q-halves (partner = w^2), then write m_g / sfac
  if (l4 == 0) {
#pragma unroll
    for (int us = 0; us < 2; ++us) {
      mS[w][us * 16 + l15] = mrun[us];
      dS[w][us * 16 + l15] = drun[us];
    }
  }
  __syncthreads();
  if (w < 2) {
#pragma unroll
    for (int us = 0; us < 2; ++us) {
      const float m2 = mS[w + 2][us * 16 + l15];
      const float d2 = dS[w + 2][us * 16 + l15];
      const float mf = fmaxf(mrun[us], m2);
      const float df = drun[us] * __expf(mrun[us] - mf) + d2 * __expf(m2 - mf);
      if (l4 == 0) {
        const long o = krow + u0 + uh * 32 + us * 16 + l15;
        m_g[o] = mf;
        sfac[o] = vproj[o] / (df + 1.0f);
      }
    }
  }
}

// ---------------------------------------------------------------------------
// Kernel B (apply): block = (qt2(256q), uc(64u), b*16+kseg(32k)), 512 thr
// (8 waves, wave tile 32q x 64u). Per k: build W2 in LDS cooperatively, MFMA,
// weighted accumulate; atomics at end. A-frags and Wal f32 in regs, k-invariant.
// ---------------------------------------------------------------------------
__global__ __launch_bounds__(512, 2) void kernelB(
    const short* __restrict__ qpF, const float* __restrict__ kproj,
    const short* __restrict__ Walb, const float* __restrict__ m_g,
    const float* __restrict__ sfac, float* __restrict__ vsum)
{
  __shared__ short W2s[64 * 264];

  const int qt2 = blockIdx.x, uc = blockIdx.y;
  const int b = blockIdx.z >> 4, kseg = blockIdx.z & 15;
  const int q0 = qt2 * 256, u0 = uc * 64, k0 = kseg * 32;
  const int tid = threadIdx.x;
  const int lane = tid & 63, w = tid >> 6;
  const int l15 = lane & 15, l4 = lane >> 4;

  // A-frags, loop-invariant: g = qt2*16 + w*2 + qs
  bf16x8 qa[2][8];
  const short* qbase = qpF + (size_t)b * 131072;
#pragma unroll
  for (int qs = 0; qs < 2; ++qs) {
    const int g = qt2 * 16 + w * 2 + qs;
#pragma unroll
    for (int ks = 0; ks < 8; ++ks)
      qa[qs][ks] = *(const bf16x8*)&qbase[((g * 8 + ks) * 64 + lane) * 8];
  }

  // Wal build-share, loop-invariant: r_i = (tid>>5) + 16*i, c8 = tid&31 (f32)
  const int c8 = tid & 31;
  const int rbase = tid >> 5;
  float walf[4][8];
#pragma unroll
  for (int i = 0; i < 4; ++i) {
    const bf16x8 wv = *(const bf16x8*)&Walb[(size_t)(u0 + rbase + 16 * i) * 256 + c8 * 8];
#pragma unroll
    for (int j = 0; j < 8; ++j) walf[i][j] = bf2f(wv[j]);
  }

  const f32x4 z4 = {0.f, 0.f, 0.f, 0.f};
  f32x4 acc[2][4] = {z4, z4, z4, z4, z4, z4, z4, z4};

#pragma unroll 1
  for (int kk = 0; kk < 32; ++kk) {
    const int k = k0 + kk;
    const long krow = (long)(b * 512 + k) * 256;

    float mv[4], sv[4];
#pragma unroll
    for (int us = 0; us < 4; ++us) {
      const long o = krow + u0 + us * 16 + l15;
      mv[us] = m_g[o];
      sv[us] = sfac[o];
    }
    const f32x4 kp0 = *(const f32x4*)&kproj[krow + c8 * 8];
    const f32x4 kp1 = *(const f32x4*)&kproj[krow + c8 * 8 + 4];

    __syncthreads();   // all waves done reading previous W2s
#pragma unroll
    for (int i = 0; i < 4; ++i) {
      uint4 st;
      st.x = packrn(walf[i][0] * kp0[0], walf[i][1] * kp0[1]);
      st.y = packrn(walf[i][2] * kp0[2], walf[i][3] * kp0[3]);
      st.z = packrn(walf[i][4] * kp1[0], walf[i][5] * kp1[1]);
      st.w = packrn(walf[i][6] * kp1[2], walf[i][7] * kp1[3]);
      *(uint4*)&W2s[(rbase + 16 * i) * 264 + c8 * 8] = st;
    }
    __syncthreads();

    f32x4 lg[2][4] = {z4, z4, z4, z4, z4, z4, z4, z4};
#pragma unroll
    for (int ks = 0; ks < 8; ++ks) {
      bf16x8 wf[4];
#pragma unroll
      for (int us = 0; us < 4; ++us)
        wf[us] = *(const bf16x8*)&W2s[(us * 16 + l15) * 264 + ks * 32 + l4 * 8];
#pragma unroll
      for (int qs = 0; qs < 2; ++qs)
#pragma unroll
        for (int us = 0; us < 4; ++us)
          lg[qs][us] = __builtin_amdgcn_mfma_f32_16x16x32_bf16(
              qa[qs][ks], wf[us], lg[qs][us], 0, 0, 0);
    }

#pragma unroll
    for (int us = 0; us < 4; ++us)
#pragma unroll
      for (int qs = 0; qs < 2; ++qs)
#pragma unroll
        for (int i = 0; i < 4; ++i) {
          const float x = lg[qs][us][i];
          acc[qs][us][i] = fmaf(sv[us] * x, __expf(x - mv[us]), acc[qs][us][i]);
        }
  }

#pragma unroll
  for (int qs = 0; qs < 2; ++qs)
#pragma unroll
    for (int us = 0; us < 4; ++us)
#pragma unroll
      for (int i = 0; i < 4; ++i)
        atomicAdd(&vsum[(size_t)(b * 512 + q0 + w * 32 + qs * 16 + l4 * 4 + i) * 256 +
                        u0 + us * 16 + l15],
                  acc[qs][us][i]);
}

extern "C" void kernel_launch(void* const* d_in, const int* in_sizes, int n_in,
                              void* d_out, int out_size, void* d_ws, size_t ws_size,
                              hipStream_t stream) {
  const float* query = (const float*)d_in[0];
  const float* key   = (const float*)d_in[1];
  const float* value = (const float*)d_in[2];
  const float* Wk    = (const float*)d_in[3];
  const float* Wq    = (const float*)d_in[4];
  const float* Wva   = (const float*)d_in[5];
  const float* Wal   = (const float*)d_in[6];
  const float* Wvo   = (const float*)d_in[7];
  float* ws = (float*)d_ws;

  float* WT    = ws;                         // 5 * 65536
  float* WkT   = WT;
  float* WqT   = WT + 65536;
  float* WvaT  = WT + 2 * 65536;
  float* WvoT  = WT + 4 * 65536;
  float* kproj = ws + 327680;
  float* vproj = kproj + 262144;
  float* m_g   = vproj + 262144;
  float* sfac  = m_g + 262144;
  float* vsum  = sfac + 262144;
  short* qpF   = (short*)(vsum + 262144);    // 262144 bf16, frag-major
  short* Walb  = qpF + 262144;               // 65536 bf16, row-major [u][t]
  float* out   = (float*)d_out;

  hipMemsetAsync(vsum, 0, 262144 * sizeof(float), stream);

  transpose5<<<dim3(256, 5), 256, 0, stream>>>(Wk, Wq, Wva, Wal, Wvo, WT);

  gemm_tn_t<0><<<dim3(16, 4), 256, 0, stream>>>(key,   WkT,  (void*)kproj);
  gemm_tn_t<0><<<dim3(16, 4), 256, 0, stream>>>(value, WvaT, (void*)vproj);
  gemm_tn_t<2><<<dim3(16, 4), 256, 0, stream>>>(query, WqT,  (void*)qpF);
  cvt_bf16x4<<<dim3(64), 256, 0, stream>>>(Wal, Walb);

  kernelA<<<dim3(512, 4, 2), 256, 0, stream>>>(qpF, kproj, vproj, Walb, m_g, sfac);
  kernelB<<<dim3(2, 4, 32), 512, 0, stream>>>(qpF, kproj, Walb, m_g, sfac, vsum);

  gemm_tn_t<0><<<dim3(16, 4), 256, 0, stream>>>(vsum, WvoT, (void*)out);
}

// Round 5
// 211.619 us; speedup vs baseline: 9.4261x; 1.4360x over previous
//
#include <hip/hip_runtime.h>
#include <cstdint>

// B=2, Q=512, K=512, T=256 (fp32 in/out).
// R5: single fused MFMA kernel (kernelC) computes logits ONCE per (k,q,u):
//   p = x*exp(x) before max is known; M = max_q x, S = sum_q |p|;
//   acc[q,u] += p * g,  g = vproj*e^-M / (S*e^-M + 1).
// Block holds all 512 q for its (k-tile, 32-u chunk): 1024 thr = 16 waves.

typedef short bf16x8 __attribute__((ext_vector_type(8)));   // 8 bf16 = 4 VGPR
typedef float f32x4  __attribute__((ext_vector_type(4)));   // MFMA C/D frag

__device__ inline float bf2f(short s) {
  return __uint_as_float(((unsigned)(unsigned short)s) << 16);
}
// f32 pair -> packed bf16 (round-half-up), low short = lo
__device__ inline unsigned packrn(float lo, float hi) {
  return __builtin_amdgcn_perm(__float_as_uint(hi) + 0x8000u,
                               __float_as_uint(lo) + 0x8000u, 0x07060302u);
}

#define FMA16()                                                                 \
  c[0][0] += a.x*w.x; c[0][1] += a.x*w.y; c[0][2] += a.x*w.z; c[0][3] += a.x*w.w; \
  c[1][0] += a.y*w.x; c[1][1] += a.y*w.y; c[1][2] += a.y*w.z; c[1][3] += a.y*w.w; \
  c[2][0] += a.z*w.x; c[2][1] += a.z*w.y; c[2][2] += a.z*w.z; c[2][3] += a.z*w.w; \
  c[3][0] += a.w*w.x; c[3][1] += a.w*w.y; c[3][2] += a.w*w.z; c[3][3] += a.w*w.w;

// GEMM inner body (fp32 VALU, 64x64 tile, 256 thr): fills c[4][4].
#define GEMM_BODY(X, WT)                                                        \
  __shared__ __align__(16) float As[16][68];                                    \
  __shared__ __align__(16) float Ws[16][64];                                    \
  const int tid = threadIdx.x;                                                  \
  const int tx4 = (tid & 15) * 4;                                               \
  const int ty4 = (tid >> 4) * 4;                                               \
  const int m0 = blockIdx.x * 64, u0 = blockIdx.y * 64;                         \
  const int lmi = tid >> 2, lc4 = (tid & 3) * 4;                                \
  const int lr  = tid >> 4, lu4 = (tid & 15) * 4;                               \
  float c[4][4] = {};                                                           \
  _Pragma("unroll 1")                                                           \
  for (int t0 = 0; t0 < 256; t0 += 16) {                                        \
    const float4 xa = *(const float4*)&(X)[(size_t)(m0 + lmi) * 256 + t0 + lc4];\
    const float4 wb = *(const float4*)&(WT)[(size_t)(t0 + lr) * 256 + u0 + lu4];\
    __syncthreads();                                                            \
    As[lc4 + 0][lmi] = xa.x; As[lc4 + 1][lmi] = xa.y;                           \
    As[lc4 + 2][lmi] = xa.z; As[lc4 + 3][lmi] = xa.w;                           \
    *(float4*)&Ws[lr][lu4] = wb;                                                \
    __syncthreads();                                                            \
    _Pragma("unroll")                                                           \
    for (int t = 0; t < 16; ++t) {                                              \
      const float4 a = *(const float4*)&As[t][ty4];                             \
      const float4 w = *(const float4*)&Ws[t][tx4];                             \
      FMA16();                                                                  \
    }                                                                           \
  }

// Prep: transpose Wk,Wq,Wva,Wvo -> WT slots 0..3; Wal -> WalF bf16 frag-major:
// WalF[((uc*32 + (t>>3))*32 + (u&31))*8 + (t&7)] = bf16(Wal[u][t]), uc = u>>5.
__global__ __launch_bounds__(256) void prep(
    const float* __restrict__ Wk, const float* __restrict__ Wq,
    const float* __restrict__ Wva, const float* __restrict__ Wvo,
    const float* __restrict__ Wal, float* __restrict__ WT,
    short* __restrict__ WalF)
{
  const int r = blockIdx.x;     // row u, 0..255
  const int m = blockIdx.y;     // 0..4
  const int t = threadIdx.x;    // 0..255 (coalesced read)
  if (m < 4) {
    const float* W = (m == 0) ? Wk : (m == 1) ? Wq : (m == 2) ? Wva : Wvo;
    WT[(size_t)m * 65536 + (size_t)t * 256 + r] = W[r * 256 + t];
  } else {
    const float v = Wal[r * 256 + t];
    const int uc = r >> 5, uu = r & 31, cc = t >> 3, j = t & 7;
    WalF[((size_t)(uc * 32 + cc) * 32 + uu) * 8 + j] = (short)packrn(v, v);
  }
}

// Batched input projections: z=0 key->kproj(f32), z=1 value->vproj(f32),
// z=2 query->qpF (bf16, MFMA A-frag-major).
__global__ __launch_bounds__(256) void proj3(
    const float* __restrict__ key, const float* __restrict__ value,
    const float* __restrict__ query, const float* __restrict__ WT,
    float* __restrict__ kproj, float* __restrict__ vproj, short* __restrict__ qpF)
{
  const int z = blockIdx.z;
  const float* X  = (z == 0) ? key : (z == 1) ? value : query;
  const float* Wt = WT + (size_t)((z == 0) ? 0 : (z == 1) ? 2 : 1) * 65536;
  GEMM_BODY(X, Wt);
  if (z == 2) {
    const int tbase = u0 + tx4;               // t coordinate
    const int ks = tbase >> 5, l4f = (tbase & 31) >> 3, j0 = tbase & 7;
#pragma unroll
    for (int i = 0; i < 4; ++i) {
      const int m = m0 + ty4 + i;             // global row = b*512 + q
      const int bb = m >> 9, q = m & 511;
      const int g = q >> 4, l15q = q & 15;
      const size_t idx = ((size_t)(((bb * 32 + g) * 8 + ks) * 64) + l4f * 16 + l15q) * 8 + j0;
      uint2 s; s.x = packrn(c[i][0], c[i][1]); s.y = packrn(c[i][2], c[i][3]);
      *(uint2*)&qpF[idx] = s;
    }
  } else {
    float* C = (z == 0) ? kproj : vproj;
#pragma unroll
    for (int i = 0; i < 4; ++i)
      *(float4*)&C[(size_t)(m0 + ty4 + i) * 256 + u0 + tx4] =
          make_float4(c[i][0], c[i][1], c[i][2], c[i][3]);
  }
}

// Final projection: out = vsum x WvoT (WT slot 3).
__global__ __launch_bounds__(256) void gemm_out(
    const float* __restrict__ X, const float* __restrict__ WT, float* __restrict__ out)
{
  GEMM_BODY(X, WT);
#pragma unroll
  for (int i = 0; i < 4; ++i)
    *(float4*)&out[(size_t)(m0 + ty4 + i) * 256 + u0 + tx4] =
        make_float4(c[i][0], c[i][1], c[i][2], c[i][3]);
}

// ---------------------------------------------------------------------------
// kernelC (fused stats+apply): grid (16 ktile, 8 uc, 2 b), 1024 thr = 16 waves.
// Wave w owns q in [w*32, w*32+32), full 32-u chunk. Per k:
//   build W2F[c8][u][8] = bf16(f32(WalF)*kp) in LDS (linear, conflict-free),
//   32 MFMA -> x tile, p = x*exp(x), wave-reduce (M,S), LDS-merge over 16
//   waves, g = vproj*e^-M/(S*e^-M+1), acc += g*p. AtomicAdd acc into vsum.
// ---------------------------------------------------------------------------
__global__ __launch_bounds__(1024, 4) void kernelC(
    const short* __restrict__ qpF, const float* __restrict__ kproj,
    const float* __restrict__ vproj, const short* __restrict__ WalF,
    float* __restrict__ vsum)
{
  __shared__ __align__(16) short W2F[8192];   // [c8][u][8] = 16 KB
  __shared__ float mS[16][32];
  __shared__ float sS[16][32];
  __shared__ float gS[32];

  const int kt = blockIdx.x, uc = blockIdx.y, b = blockIdx.z;
  const int u0 = uc * 32, k0 = kt * 32;
  const int tid = threadIdx.x;
  const int lane = tid & 63, w = tid >> 6;
  const int l15 = lane & 15, l4 = lane >> 4;
  const int c8 = tid >> 5;

  // k-invariant Wal build fragment (f32)
  float wvf[8];
  {
    const bf16x8 wv = *(const bf16x8*)&WalF[((size_t)uc * 1024 + tid) * 8];
#pragma unroll
    for (int j = 0; j < 8; ++j) wvf[j] = bf2f(wv[j]);
  }

  const short* qbase = qpF + (size_t)b * 131072;
  const f32x4 z4 = {0.f, 0.f, 0.f, 0.f};
  f32x4 acc[2][2] = {z4, z4, z4, z4};

#pragma unroll 1
  for (int kk = 0; kk < 32; ++kk) {
    const int k = k0 + kk;
    const long krow = (long)(b * 512 + k) * 256;
    const f32x4 kp0 = *(const f32x4*)&kproj[krow + c8 * 8];
    const f32x4 kp1 = *(const f32x4*)&kproj[krow + c8 * 8 + 4];
    __syncthreads();                      // prev k: W2F / gS readers done
    {
      uint4 st;
      st.x = packrn(wvf[0] * kp0[0], wvf[1] * kp0[1]);
      st.y = packrn(wvf[2] * kp0[2], wvf[3] * kp0[3]);
      st.z = packrn(wvf[4] * kp1[0], wvf[5] * kp1[1]);
      st.w = packrn(wvf[6] * kp1[2], wvf[7] * kp1[3]);
      *(uint4*)&W2F[tid * 8] = st;
    }
    __syncthreads();

    f32x4 lg[2][2] = {z4, z4, z4, z4};
#pragma unroll
    for (int ks = 0; ks < 8; ++ks) {
      const bf16x8 qa0 = *(const bf16x8*)&qbase[(((w * 2 + 0) * 8 + ks) * 64 + lane) * 8];
      const bf16x8 qa1 = *(const bf16x8*)&qbase[(((w * 2 + 1) * 8 + ks) * 64 + lane) * 8];
      const bf16x8 wf0 = *(const bf16x8*)&W2F[(((ks * 4 + l4) * 32) + l15) * 8];
      const bf16x8 wf1 = *(const bf16x8*)&W2F[(((ks * 4 + l4) * 32) + 16 + l15) * 8];
      lg[0][0] = __builtin_amdgcn_mfma_f32_16x16x32_bf16(qa0, wf0, lg[0][0], 0, 0, 0);
      lg[1][0] = __builtin_amdgcn_mfma_f32_16x16x32_bf16(qa1, wf0, lg[1][0], 0, 0, 0);
      lg[0][1] = __builtin_amdgcn_mfma_f32_16x16x32_bf16(qa0, wf1, lg[0][1], 0, 0, 0);
      lg[1][1] = __builtin_amdgcn_mfma_f32_16x16x32_bf16(qa1, wf1, lg[1][1], 0, 0, 0);
    }

    // p = x*exp(x) (overwrite lg); per-u M = max x, S = sum|p|; reduce in wave
#pragma unroll
    for (int ug = 0; ug < 2; ++ug) {
      float m = lg[0][ug][0];
#pragma unroll
      for (int qg = 0; qg < 2; ++qg)
#pragma unroll
        for (int i = 0; i < 4; ++i) m = fmaxf(m, lg[qg][ug][i]);
      float s = 0.f;
#pragma unroll
      for (int qg = 0; qg < 2; ++qg)
#pragma unroll
        for (int i = 0; i < 4; ++i) {
          const float x = lg[qg][ug][i];
          const float p = x * __expf(x);
          lg[qg][ug][i] = p;
          s += fabsf(p);
        }
      m = fmaxf(m, __shfl_xor(m, 16));
      m = fmaxf(m, __shfl_xor(m, 32));
      s += __shfl_xor(s, 16);
      s += __shfl_xor(s, 32);
      if (l4 == 0) { mS[w][ug * 16 + l15] = m; sS[w][ug * 16 + l15] = s; }
    }
    __syncthreads();
    if (tid < 32) {
      float M = mS[0][tid], S = sS[0][tid];
#pragma unroll
      for (int r = 1; r < 16; ++r) { M = fmaxf(M, mS[r][tid]); S += sS[r][tid]; }
      const float em = __expf(-M);
      gS[tid] = vproj[krow + u0 + tid] * em / fmaf(S, em, 1.0f);
    }
    __syncthreads();
    const float g0 = gS[l15], g1 = gS[16 + l15];
#pragma unroll
    for (int qg = 0; qg < 2; ++qg)
#pragma unroll
      for (int i = 0; i < 4; ++i) {
        acc[qg][0][i] = fmaf(g0, lg[qg][0][i], acc[qg][0][i]);
        acc[qg][1][i] = fmaf(g1, lg[qg][1][i], acc[qg][1][i]);
      }
  }

#pragma unroll
  for (int qg = 0; qg < 2; ++qg)
#pragma unroll
    for (int ug = 0; ug < 2; ++ug)
#pragma unroll
      for (int i = 0; i < 4; ++i)
        atomicAdd(&vsum[(size_t)(b * 512 + w * 32 + qg * 16 + l4 * 4 + i) * 256 +
                        u0 + ug * 16 + l15],
                  acc[qg][ug][i]);
}

extern "C" void kernel_launch(void* const* d_in, const int* in_sizes, int n_in,
                              void* d_out, int out_size, void* d_ws, size_t ws_size,
                              hipStream_t stream) {
  const float* query = (const float*)d_in[0];
  const float* key   = (const float*)d_in[1];
  const float* value = (const float*)d_in[2];
  const float* Wk    = (const float*)d_in[3];
  const float* Wq    = (const float*)d_in[4];
  const float* Wva   = (const float*)d_in[5];
  const float* Wal   = (const float*)d_in[6];
  const float* Wvo   = (const float*)d_in[7];
  float* ws = (float*)d_ws;

  float* WT    = ws;                        // 4 * 65536 (Wk, Wq, Wva, Wvo)
  float* kproj = ws + 262144;
  float* vproj = kproj + 262144;
  float* vsum  = vproj + 262144;
  short* qpF   = (short*)(vsum + 262144);   // 262144 bf16, frag-major
  short* WalF  = qpF + 262144;              // 65536 bf16, frag-major
  float* out   = (float*)d_out;

  hipMemsetAsync(vsum, 0, 262144 * sizeof(float), stream);

  prep<<<dim3(256, 5), 256, 0, stream>>>(Wk, Wq, Wva, Wvo, Wal, WT, WalF);
  proj3<<<dim3(16, 4, 3), 256, 0, stream>>>(key, value, query, WT, kproj, vproj, qpF);
  kernelC<<<dim3(16, 8, 2), 1024, 0, stream>>>(qpF, kproj, vproj, WalF, vsum);
  gemm_out<<<dim3(16, 4), 256, 0, stream>>>(vsum, WT + 3 * 65536, out);
}

// Round 6
// 201.477 us; speedup vs baseline: 9.9006x; 1.0503x over previous
//
#include <hip/hip_runtime.h>
#include <cstdint>

// B=2, Q=512, K=512, T=256 (fp32 in/out).
// R6: fused kernelC with k-invariant data resident: qa frags in 64 VGPRs
// (loaded once), vproj tile preloaded to LDS, padded parallel reduce.
//   p = x*exp(x); M = max_q x, S = sum_q |p|; acc += p * g,
//   g = vproj*e^-M / (S*e^-M + 1).

typedef short bf16x8 __attribute__((ext_vector_type(8)));   // 8 bf16 = 4 VGPR
typedef float f32x4  __attribute__((ext_vector_type(4)));   // MFMA C/D frag

__device__ inline float bf2f(short s) {
  return __uint_as_float(((unsigned)(unsigned short)s) << 16);
}
// f32 pair -> packed bf16 (round-half-up), low short = lo
__device__ inline unsigned packrn(float lo, float hi) {
  return __builtin_amdgcn_perm(__float_as_uint(hi) + 0x8000u,
                               __float_as_uint(lo) + 0x8000u, 0x07060302u);
}

#define FMA16()                                                                 \
  c[0][0] += a.x*w.x; c[0][1] += a.x*w.y; c[0][2] += a.x*w.z; c[0][3] += a.x*w.w; \
  c[1][0] += a.y*w.x; c[1][1] += a.y*w.y; c[1][2] += a.y*w.z; c[1][3] += a.y*w.w; \
  c[2][0] += a.z*w.x; c[2][1] += a.z*w.y; c[2][2] += a.z*w.z; c[2][3] += a.z*w.w; \
  c[3][0] += a.w*w.x; c[3][1] += a.w*w.y; c[3][2] += a.w*w.z; c[3][3] += a.w*w.w;

// GEMM inner body (fp32 VALU, 64x64 tile, 256 thr): fills c[4][4].
#define GEMM_BODY(X, WT)                                                        \
  __shared__ __align__(16) float As[16][68];                                    \
  __shared__ __align__(16) float Ws[16][64];                                    \
  const int tid = threadIdx.x;                                                  \
  const int tx4 = (tid & 15) * 4;                                               \
  const int ty4 = (tid >> 4) * 4;                                               \
  const int m0 = blockIdx.x * 64, u0 = blockIdx.y * 64;                         \
  const int lmi = tid >> 2, lc4 = (tid & 3) * 4;                                \
  const int lr  = tid >> 4, lu4 = (tid & 15) * 4;                               \
  float c[4][4] = {};                                                           \
  _Pragma("unroll 1")                                                           \
  for (int t0 = 0; t0 < 256; t0 += 16) {                                        \
    const float4 xa = *(const float4*)&(X)[(size_t)(m0 + lmi) * 256 + t0 + lc4];\
    const float4 wb = *(const float4*)&(WT)[(size_t)(t0 + lr) * 256 + u0 + lu4];\
    __syncthreads();                                                            \
    As[lc4 + 0][lmi] = xa.x; As[lc4 + 1][lmi] = xa.y;                           \
    As[lc4 + 2][lmi] = xa.z; As[lc4 + 3][lmi] = xa.w;                           \
    *(float4*)&Ws[lr][lu4] = wb;                                                \
    __syncthreads();                                                            \
    _Pragma("unroll")                                                           \
    for (int t = 0; t < 16; ++t) {                                              \
      const float4 a = *(const float4*)&As[t][ty4];                             \
      const float4 w = *(const float4*)&Ws[t][tx4];                             \
      FMA16();                                                                  \
    }                                                                           \
  }

// Prep: transpose Wk,Wq,Wva,Wvo -> WT slots 0..3; Wal -> WalF bf16 frag-major;
// m==5: zero vsum (fused memset).
__global__ __launch_bounds__(256) void prep(
    const float* __restrict__ Wk, const float* __restrict__ Wq,
    const float* __restrict__ Wva, const float* __restrict__ Wvo,
    const float* __restrict__ Wal, float* __restrict__ WT,
    short* __restrict__ WalF, float* __restrict__ vsum)
{
  const int r = blockIdx.x;     // row u, 0..255
  const int m = blockIdx.y;     // 0..5
  const int t = threadIdx.x;    // 0..255 (coalesced read)
  if (m < 4) {
    const float* W = (m == 0) ? Wk : (m == 1) ? Wq : (m == 2) ? Wva : Wvo;
    WT[(size_t)m * 65536 + (size_t)t * 256 + r] = W[r * 256 + t];
  } else if (m == 4) {
    const float v = Wal[r * 256 + t];
    const int uc = r >> 5, uu = r & 31, cc = t >> 3, j = t & 7;
    WalF[((size_t)(uc * 32 + cc) * 32 + uu) * 8 + j] = (short)packrn(v, v);
  } else {
    *(float4*)&vsum[(size_t)(r * 256 + t) * 4] = make_float4(0.f, 0.f, 0.f, 0.f);
  }
}

// Batched input projections: z=0 key->kproj(f32), z=1 value->vproj(f32),
// z=2 query->qpF (bf16, MFMA A-frag-major).
__global__ __launch_bounds__(256) void proj3(
    const float* __restrict__ key, const float* __restrict__ value,
    const float* __restrict__ query, const float* __restrict__ WT,
    float* __restrict__ kproj, float* __restrict__ vproj, short* __restrict__ qpF)
{
  const int z = blockIdx.z;
  const float* X  = (z == 0) ? key : (z == 1) ? value : query;
  const float* Wt = WT + (size_t)((z == 0) ? 0 : (z == 1) ? 2 : 1) * 65536;
  GEMM_BODY(X, Wt);
  if (z == 2) {
    const int tbase = u0 + tx4;               // t coordinate
    const int ks = tbase >> 5, l4f = (tbase & 31) >> 3, j0 = tbase & 7;
#pragma unroll
    for (int i = 0; i < 4; ++i) {
      const int m = m0 + ty4 + i;             // global row = b*512 + q
      const int bb = m >> 9, q = m & 511;
      const int g = q >> 4, l15q = q & 15;
      const size_t idx = ((size_t)(((bb * 32 + g) * 8 + ks) * 64) + l4f * 16 + l15q) * 8 + j0;
      uint2 s; s.x = packrn(c[i][0], c[i][1]); s.y = packrn(c[i][2], c[i][3]);
      *(uint2*)&qpF[idx] = s;
    }
  } else {
    float* C = (z == 0) ? kproj : vproj;
#pragma unroll
    for (int i = 0; i < 4; ++i)
      *(float4*)&C[(size_t)(m0 + ty4 + i) * 256 + u0 + tx4] =
          make_float4(c[i][0], c[i][1], c[i][2], c[i][3]);
  }
}

// Final projection: out = vsum x WvoT (WT slot 3).
__global__ __launch_bounds__(256) void gemm_out(
    const float* __restrict__ X, const float* __restrict__ WT, float* __restrict__ out)
{
  GEMM_BODY(X, WT);
#pragma unroll
  for (int i = 0; i < 4; ++i)
    *(float4*)&out[(size_t)(m0 + ty4 + i) * 256 + u0 + tx4] =
        make_float4(c[i][0], c[i][1], c[i][2], c[i][3]);
}

// ---------------------------------------------------------------------------
// kernelC (fused stats+apply): grid (16 ktile, 8 uc, 2 b), 1024 thr = 16 waves.
// Wave w owns q in [w*32, w*32+32), full 32-u chunk. qa frags persistent in
// VGPRs (loaded once). Per k: build W2F in LDS (linear, conflict-free),
// 32 MFMA -> x, p = x*exp(x), wave-reduce (M,S), LDS merge over 16 waves
// (padded, LDS-only), g from preloaded vpS, acc += g*p. AtomicAdd at end.
// ---------------------------------------------------------------------------
__global__ __launch_bounds__(1024, 1) void kernelC(
    const short* __restrict__ qpF, const float* __restrict__ kproj,
    const float* __restrict__ vproj, const short* __restrict__ WalF,
    float* __restrict__ vsum)
{
  __shared__ __align__(16) short W2F[8192];   // [c8][u][8] = 16 KB
  __shared__ float vpS[32 * 33];              // vproj tile [kk][u], padded
  __shared__ float mS[16 * 33];               // [w][u], padded
  __shared__ float sS[16 * 33];
  __shared__ float gS[32];

  const int kt = blockIdx.x, uc = blockIdx.y, b = blockIdx.z;
  const int u0 = uc * 32, k0 = kt * 32;
  const int tid = threadIdx.x;
  const int lane = tid & 63, w = tid >> 6;
  const int l15 = lane & 15, l4 = lane >> 4;
  const int c8 = tid >> 5;

  // k-invariant Wal build fragment (bf16, expanded at build time)
  const bf16x8 wvb = *(const bf16x8*)&WalF[((size_t)uc * 1024 + tid) * 8];
  float wvf[8];
#pragma unroll
  for (int j = 0; j < 8; ++j) wvf[j] = bf2f(wvb[j]);

  // preload vproj tile: kk = tid>>5, uu = tid&31
  vpS[(tid >> 5) * 33 + (tid & 31)] =
      vproj[(size_t)(b * 512 + k0 + (tid >> 5)) * 256 + u0 + (tid & 31)];

  // persistent A-fragments: 32 q x 256 t for this wave (64 VGPR)
  const short* qbase = qpF + (size_t)b * 131072;
  bf16x8 qa[2][8];
#pragma unroll
  for (int qg = 0; qg < 2; ++qg)
#pragma unroll
    for (int ks = 0; ks < 8; ++ks)
      qa[qg][ks] = *(const bf16x8*)&qbase[(((w * 2 + qg) * 8 + ks) * 64 + lane) * 8];

  const f32x4 z4 = {0.f, 0.f, 0.f, 0.f};
  f32x4 acc[2][2] = {z4, z4, z4, z4};

#pragma unroll 1
  for (int kk = 0; kk < 32; ++kk) {
    const long krow = (long)(b * 512 + k0 + kk) * 256;
    const f32x4 kp0 = *(const f32x4*)&kproj[krow + c8 * 8];
    const f32x4 kp1 = *(const f32x4*)&kproj[krow + c8 * 8 + 4];
    __syncthreads();                      // prev k: W2F / gS readers done
    {
      uint4 st;
      st.x = packrn(wvf[0] * kp0[0], wvf[1] * kp0[1]);
      st.y = packrn(wvf[2] * kp0[2], wvf[3] * kp0[3]);
      st.z = packrn(wvf[4] * kp1[0], wvf[5] * kp1[1]);
      st.w = packrn(wvf[6] * kp1[2], wvf[7] * kp1[3]);
      *(uint4*)&W2F[tid * 8] = st;
    }
    __syncthreads();

    f32x4 lg[2][2] = {z4, z4, z4, z4};
#pragma unroll
    for (int ks = 0; ks < 8; ++ks) {
      const bf16x8 wf0 = *(const bf16x8*)&W2F[(((ks * 4 + l4) * 32) + l15) * 8];
      const bf16x8 wf1 = *(const bf16x8*)&W2F[(((ks * 4 + l4) * 32) + 16 + l15) * 8];
      lg[0][0] = __builtin_amdgcn_mfma_f32_16x16x32_bf16(qa[0][ks], wf0, lg[0][0], 0, 0, 0);
      lg[1][0] = __builtin_amdgcn_mfma_f32_16x16x32_bf16(qa[1][ks], wf0, lg[1][0], 0, 0, 0);
      lg[0][1] = __builtin_amdgcn_mfma_f32_16x16x32_bf16(qa[0][ks], wf1, lg[0][1], 0, 0, 0);
      lg[1][1] = __builtin_amdgcn_mfma_f32_16x16x32_bf16(qa[1][ks], wf1, lg[1][1], 0, 0, 0);
    }

    // p = x*exp(x) (overwrite lg); per-u M = max x, S = sum|p|; wave-reduce
#pragma unroll
    for (int ug = 0; ug < 2; ++ug) {
      float m = lg[0][ug][0];
#pragma unroll
      for (int qg = 0; qg < 2; ++qg)
#pragma unroll
        for (int i = 0; i < 4; ++i) m = fmaxf(m, lg[qg][ug][i]);
      float s = 0.f;
#pragma unroll
      for (int qg = 0; qg < 2; ++qg)
#pragma unroll
        for (int i = 0; i < 4; ++i) {
          const float x = lg[qg][ug][i];
          const float p = x * __expf(x);
          lg[qg][ug][i] = p;
          s += fabsf(p);
        }
      m = fmaxf(m, __shfl_xor(m, 16));
      m = fmaxf(m, __shfl_xor(m, 32));
      s += __shfl_xor(s, 16);
      s += __shfl_xor(s, 32);
      if (l4 == 0) { mS[w * 33 + ug * 16 + l15] = m; sS[w * 33 + ug * 16 + l15] = s; }
    }
    __syncthreads();
    if (tid < 32) {
      float M = mS[tid], S = sS[tid];
#pragma unroll
      for (int r = 1; r < 16; ++r) { M = fmaxf(M, mS[r * 33 + tid]); S += sS[r * 33 + tid]; }
      const float em = __expf(-M);
      gS[tid] = vpS[kk * 33 + tid] * em / fmaf(S, em, 1.0f);
    }
    __syncthreads();
    const float g0 = gS[l15], g1 = gS[16 + l15];
#pragma unroll
    for (int qg = 0; qg < 2; ++qg)
#pragma unroll
      for (int i = 0; i < 4; ++i) {
        acc[qg][0][i] = fmaf(g0, lg[qg][0][i], acc[qg][0][i]);
        acc[qg][1][i] = fmaf(g1, lg[qg][1][i], acc[qg][1][i]);
      }
  }

#pragma unroll
  for (int qg = 0; qg < 2; ++qg)
#pragma unroll
    for (int ug = 0; ug < 2; ++ug)
#pragma unroll
      for (int i = 0; i < 4; ++i)
        atomicAdd(&vsum[(size_t)(b * 512 + w * 32 + qg * 16 + l4 * 4 + i) * 256 +
                        u0 + ug * 16 + l15],
                  acc[qg][ug][i]);
}

extern "C" void kernel_launch(void* const* d_in, const int* in_sizes, int n_in,
                              void* d_out, int out_size, void* d_ws, size_t ws_size,
                              hipStream_t stream) {
  const float* query = (const float*)d_in[0];
  const float* key   = (const float*)d_in[1];
  const float* value = (const float*)d_in[2];
  const float* Wk    = (const float*)d_in[3];
  const float* Wq    = (const float*)d_in[4];
  const float* Wva   = (const float*)d_in[5];
  const float* Wal   = (const float*)d_in[6];
  const float* Wvo   = (const float*)d_in[7];
  float* ws = (float*)d_ws;

  float* WT    = ws;                        // 4 * 65536 (Wk, Wq, Wva, Wvo)
  float* kproj = ws + 262144;
  float* vproj = kproj + 262144;
  float* vsum  = vproj + 262144;
  short* qpF   = (short*)(vsum + 262144);   // 262144 bf16, frag-major
  short* WalF  = qpF + 262144;              // 65536 bf16, frag-major
  float* out   = (float*)d_out;

  prep<<<dim3(256, 6), 256, 0, stream>>>(Wk, Wq, Wva, Wvo, Wal, WT, WalF, vsum);
  proj3<<<dim3(16, 4, 3), 256, 0, stream>>>(key, value, query, WT, kproj, vproj, qpF);
  kernelC<<<dim3(16, 8, 2), 1024, 0, stream>>>(qpF, kproj, vproj, WalF, vsum);
  gemm_out<<<dim3(16, 4), 256, 0, stream>>>(vsum, WT + 3 * 65536, out);
}

// Round 7
// 197.803 us; speedup vs baseline: 10.0845x; 1.0186x over previous
//
#include <hip/hip_runtime.h>
#include <cstdint>

// B=2, Q=512, K=512, T=256 (fp32 in/out).
// R7: fused kernelC, 8 waves x (64q x 32u), qa pinned in 128 VGPRs,
// double-buffered W2F (1 barrier/k), stats via LDS atomics (3-slot rotation).
//   p = x*exp(x); M = max_q x, S = sum_q |p|; acc += p * g,
//   g = vproj*e^-M / (S*e^-M + 1).

typedef short bf16x8 __attribute__((ext_vector_type(8)));   // 8 bf16 = 4 VGPR
typedef float f32x4  __attribute__((ext_vector_type(4)));   // MFMA C/D frag

__device__ inline float bf2f(short s) {
  return __uint_as_float(((unsigned)(unsigned short)s) << 16);
}
// f32 pair -> packed bf16 (round-half-up), low short = lo
__device__ inline unsigned packrn(float lo, float hi) {
  return __builtin_amdgcn_perm(__float_as_uint(hi) + 0x8000u,
                               __float_as_uint(lo) + 0x8000u, 0x07060302u);
}
// monotone (unsigned) encoding of f32 for atomic max; 0 == "-infinity" sentinel
__device__ inline unsigned encM(float f) {
  unsigned k = (unsigned)__float_as_int(f);
  return (k & 0x80000000u) ? ~k : (k | 0x80000000u);
}
__device__ inline float decM(unsigned k) {
  int i = (k & 0x80000000u) ? (int)(k ^ 0x80000000u) : (int)~k;
  return __int_as_float(i);
}

#define FMA16()                                                                 \
  c[0][0] += a.x*w.x; c[0][1] += a.x*w.y; c[0][2] += a.x*w.z; c[0][3] += a.x*w.w; \
  c[1][0] += a.y*w.x; c[1][1] += a.y*w.y; c[1][2] += a.y*w.z; c[1][3] += a.y*w.w; \
  c[2][0] += a.z*w.x; c[2][1] += a.z*w.y; c[2][2] += a.z*w.z; c[2][3] += a.z*w.w; \
  c[3][0] += a.w*w.x; c[3][1] += a.w*w.y; c[3][2] += a.w*w.z; c[3][3] += a.w*w.w;

// GEMM body, W row-major (transposed through LDS on load). 64x64 tile, 256 thr.
#define GEMM_BODY_RM(X, W)                                                      \
  __shared__ __align__(16) float As[16][68];                                    \
  __shared__ __align__(16) float Ws[16][68];                                    \
  const int tid = threadIdx.x;                                                  \
  const int tx4 = (tid & 15) * 4;                                               \
  const int ty4 = (tid >> 4) * 4;                                               \
  const int m0 = blockIdx.x * 64, u0 = blockIdx.y * 64;                         \
  const int lmi = tid >> 2, lc4 = (tid & 3) * 4;                                \
  float c[4][4] = {};                                                           \
  _Pragma("unroll 1")                                                           \
  for (int t0 = 0; t0 < 256; t0 += 16) {                                        \
    const float4 xa = *(const float4*)&(X)[(size_t)(m0 + lmi) * 256 + t0 + lc4];\
    const float4 wb = *(const float4*)&(W)[(size_t)(u0 + lmi) * 256 + t0 + lc4];\
    __syncthreads();                                                            \
    As[lc4 + 0][lmi] = xa.x; As[lc4 + 1][lmi] = xa.y;                           \
    As[lc4 + 2][lmi] = xa.z; As[lc4 + 3][lmi] = xa.w;                           \
    Ws[lc4 + 0][lmi] = wb.x; Ws[lc4 + 1][lmi] = wb.y;                           \
    Ws[lc4 + 2][lmi] = wb.z; Ws[lc4 + 3][lmi] = wb.w;                           \
    __syncthreads();                                                            \
    _Pragma("unroll")                                                           \
    for (int t = 0; t < 16; ++t) {                                              \
      const float4 a = *(const float4*)&As[t][ty4];                             \
      const float4 w = *(const float4*)&Ws[t][tx4];                             \
      FMA16();                                                                  \
    }                                                                           \
  }

// Projections + aux. z=0 key->kproj(f32), z=1 value->vproj(f32),
// z=2 query->qpF (bf16 A-frag-major), z=3: WalF build + vsum zero.
__global__ __launch_bounds__(256) void proj3(
    const float* __restrict__ key, const float* __restrict__ value,
    const float* __restrict__ query, const float* __restrict__ Wk,
    const float* __restrict__ Wq, const float* __restrict__ Wva,
    const float* __restrict__ Wal, float* __restrict__ kproj,
    float* __restrict__ vproj, short* __restrict__ qpF,
    short* __restrict__ WalF, float* __restrict__ vsum)
{
  const int z = blockIdx.z;
  if (z == 3) {
    const int p = blockIdx.x * 4 + blockIdx.y;    // 0..63
    const int t256 = threadIdx.x;
    // WalF: frag-major bf16 copy of Wal; 1024 shorts per block
#pragma unroll
    for (int e = 0; e < 4; ++e) {
      const int d = p * 1024 + t256 * 4 + e;
      const int j = d & 7, uu = (d >> 3) & 31, c8g = d >> 8;
      const int ucx = c8g >> 5, cc = c8g & 31;
      const float v = Wal[(ucx * 32 + uu) * 256 + cc * 8 + j];
      WalF[d] = (short)packrn(v, v);
    }
    // vsum zero: 4096 floats per block
    float4* vz = (float4*)(vsum + p * 4096);
#pragma unroll
    for (int e = 0; e < 4; ++e) vz[t256 * 4 + e] = make_float4(0.f, 0.f, 0.f, 0.f);
    return;
  }
  const float* X = (z == 0) ? key : (z == 1) ? value : query;
  const float* W = (z == 0) ? Wk  : (z == 1) ? Wva   : Wq;
  GEMM_BODY_RM(X, W);
  if (z == 2) {
    const int tbase = u0 + tx4;               // t coordinate
    const int ks = tbase >> 5, l4f = (tbase & 31) >> 3, j0 = tbase & 7;
#pragma unroll
    for (int i = 0; i < 4; ++i) {
      const int m = m0 + ty4 + i;             // global row = b*512 + q
      const int bb = m >> 9, q = m & 511;
      const int g = q >> 4, l15q = q & 15;
      const size_t idx = ((size_t)(((bb * 32 + g) * 8 + ks) * 64) + l4f * 16 + l15q) * 8 + j0;
      uint2 s; s.x = packrn(c[i][0], c[i][1]); s.y = packrn(c[i][2], c[i][3]);
      *(uint2*)&qpF[idx] = s;
    }
  } else {
    float* C = (z == 0) ? kproj : vproj;
#pragma unroll
    for (int i = 0; i < 4; ++i)
      *(float4*)&C[(size_t)(m0 + ty4 + i) * 256 + u0 + tx4] =
          make_float4(c[i][0], c[i][1], c[i][2], c[i][3]);
  }
}

// Final projection: out = vsum x Wvo^T (Wvo row-major).
__global__ __launch_bounds__(256) void gemm_out(
    const float* __restrict__ X, const float* __restrict__ W, float* __restrict__ out)
{
  GEMM_BODY_RM(X, W);
#pragma unroll
  for (int i = 0; i < 4; ++i)
    *(float4*)&out[(size_t)(m0 + ty4 + i) * 256 + u0 + tx4] =
        make_float4(c[i][0], c[i][1], c[i][2], c[i][3]);
}

union Frag { bf16x8 v; unsigned u[4]; };

// ---------------------------------------------------------------------------
// kernelC: grid (16 kt, 8 uc, 2 b), 512 thr = 8 waves; wave w: q in
// [w*64, w*64+64), full 32-u chunk. qa (64q x 256t bf16 = 128 VGPR) pinned.
// Per k (ONE barrier): MFMA from W2F[k&1]; build W2F[(k+1)&1]; stats via
// shfl + LDS atomics into slot k%3; barrier; per-lane g; apply; reset slot
// (k+2)%3. 3-slot rotation keeps reset/atomic windows barrier-separated.
// ---------------------------------------------------------------------------
__global__ __launch_bounds__(512, 2) void kernelC(
    const short* __restrict__ qpF, const float* __restrict__ kproj,
    const float* __restrict__ vproj, const short* __restrict__ WalF,
    float* __restrict__ vsum)
{
  __shared__ __align__(16) short W2F[2][8192];  // 2 x 16 KB, [c8][u][8]
  __shared__ float vpS[32 * 33];                // vproj tile [kk][u], padded
  __shared__ unsigned statM[96];                // 3 slots x 32 u (encoded max)
  __shared__ float statS[96];                   // 3 slots x 32 u

  const int kt = blockIdx.x, uc = blockIdx.y, b = blockIdx.z;
  const int u0 = uc * 32, k0 = kt * 32;
  const int tid = threadIdx.x;
  const int lane = tid & 63, w = tid >> 6;
  const int l15 = lane & 15, l4 = lane >> 4;
  const int uu = tid & 31, c8 = tid >> 5;       // build mapping: c8 and c8+16

  if (tid < 96) { statM[tid] = 0u; statS[tid] = 0.f; }
  {
    const int kk = tid >> 4, uu2 = (tid & 15) * 2;
    const float2 v2 = *(const float2*)&vproj[(size_t)(b * 512 + k0 + kk) * 256 + u0 + uu2];
    vpS[kk * 33 + uu2] = v2.x; vpS[kk * 33 + uu2 + 1] = v2.y;
  }

  // k-invariant Wal build octets (f32-expanded, 16 VGPR)
  float wl0[8], wl1[8];
  {
    const bf16x8 w0 = *(const bf16x8*)&WalF[((size_t)(uc * 32 + c8) * 32 + uu) * 8];
    const bf16x8 w1 = *(const bf16x8*)&WalF[((size_t)(uc * 32 + c8 + 16) * 32 + uu) * 8];
#pragma unroll
    for (int j = 0; j < 8; ++j) { wl0[j] = bf2f(w0[j]); wl1[j] = bf2f(w1[j]); }
  }

  // persistent A-fragments (128 VGPR), pinned against rematerialization
  const short* qbase = qpF + (size_t)b * 131072;
  Frag qa[4][8];
#pragma unroll
  for (int qg = 0; qg < 4; ++qg)
#pragma unroll
    for (int ks = 0; ks < 8; ++ks) {
      qa[qg][ks].v = *(const bf16x8*)&qbase[(((size_t)(w * 4 + qg) * 8 + ks) * 64 + lane) * 8];
      asm volatile("" : "+v"(qa[qg][ks].u[0]), "+v"(qa[qg][ks].u[1]),
                        "+v"(qa[qg][ks].u[2]), "+v"(qa[qg][ks].u[3]));
    }

  // prologue: build W2F[0] for k = k0
  {
    const long krow = (long)(b * 512 + k0) * 256;
    const f32x4 a0 = *(const f32x4*)&kproj[krow + c8 * 8];
    const f32x4 a1 = *(const f32x4*)&kproj[krow + c8 * 8 + 4];
    const f32x4 b0 = *(const f32x4*)&kproj[krow + (c8 + 16) * 8];
    const f32x4 b1 = *(const f32x4*)&kproj[krow + (c8 + 16) * 8 + 4];
    uint4 st;
    st.x = packrn(wl0[0] * a0[0], wl0[1] * a0[1]);
    st.y = packrn(wl0[2] * a0[2], wl0[3] * a0[3]);
    st.z = packrn(wl0[4] * a1[0], wl0[5] * a1[1]);
    st.w = packrn(wl0[6] * a1[2], wl0[7] * a1[3]);
    *(uint4*)&W2F[0][(c8 * 32 + uu) * 8] = st;
    st.x = packrn(wl1[0] * b0[0], wl1[1] * b0[1]);
    st.y = packrn(wl1[2] * b0[2], wl1[3] * b0[3]);
    st.z = packrn(wl1[4] * b1[0], wl1[5] * b1[1]);
    st.w = packrn(wl1[6] * b1[2], wl1[7] * b1[3]);
    *(uint4*)&W2F[0][((c8 + 16) * 32 + uu) * 8] = st;
  }
  __syncthreads();

  const f32x4 z4 = {0.f, 0.f, 0.f, 0.f};
  f32x4 acc[4][2] = {z4, z4, z4, z4, z4, z4, z4, z4};

#pragma unroll 1
  for (int kk = 0; kk < 32; ++kk) {
    const int cs = kk & 1, ss = kk % 3;

    // issue next k's kp loads early (hidden under MFMA)
    f32x4 a0, a1, b0, b1;
    if (kk < 31) {
      const long krn = (long)(b * 512 + k0 + kk + 1) * 256;
      a0 = *(const f32x4*)&kproj[krn + c8 * 8];
      a1 = *(const f32x4*)&kproj[krn + c8 * 8 + 4];
      b0 = *(const f32x4*)&kproj[krn + (c8 + 16) * 8];
      b1 = *(const f32x4*)&kproj[krn + (c8 + 16) * 8 + 4];
    }

    f32x4 lg[4][2] = {z4, z4, z4, z4, z4, z4, z4, z4};
#pragma unroll
    for (int ks = 0; ks < 8; ++ks) {
      const bf16x8 f0 = *(const bf16x8*)&W2F[cs][((ks * 4 + l4) * 32 + l15) * 8];
      const bf16x8 f1 = *(const bf16x8*)&W2F[cs][((ks * 4 + l4) * 32 + 16 + l15) * 8];
#pragma unroll
      for (int qg = 0; qg < 4; ++qg) {
        lg[qg][0] = __builtin_amdgcn_mfma_f32_16x16x32_bf16(qa[qg][ks].v, f0, lg[qg][0], 0, 0, 0);
        lg[qg][1] = __builtin_amdgcn_mfma_f32_16x16x32_bf16(qa[qg][ks].v, f1, lg[qg][1], 0, 0, 0);
      }
    }

    // build next slot (write-after-read safe: slot read last at kk-1, barrier between)
    if (kk < 31) {
      uint4 st;
      st.x = packrn(wl0[0] * a0[0], wl0[1] * a0[1]);
      st.y = packrn(wl0[2] * a0[2], wl0[3] * a0[3]);
      st.z = packrn(wl0[4] * a1[0], wl0[5] * a1[1]);
      st.w = packrn(wl0[6] * a1[2], wl0[7] * a1[3]);
      *(uint4*)&W2F[cs ^ 1][(c8 * 32 + uu) * 8] = st;
      st.x = packrn(wl1[0] * b0[0], wl1[1] * b0[1]);
      st.y = packrn(wl1[2] * b0[2], wl1[3] * b0[3]);
      st.z = packrn(wl1[4] * b1[0], wl1[5] * b1[1]);
      st.w = packrn(wl1[6] * b1[2], wl1[7] * b1[3]);
      *(uint4*)&W2F[cs ^ 1][((c8 + 16) * 32 + uu) * 8] = st;
    }

    // stats: M = max x (before overwrite), p = x*exp(x), S = sum|p|
    float Mv[2], Sv[2];
#pragma unroll
    for (int ug = 0; ug < 2; ++ug) {
      float m = lg[0][ug][0];
#pragma unroll
      for (int qg = 0; qg < 4; ++qg)
#pragma unroll
        for (int i = 0; i < 4; ++i) m = fmaxf(m, lg[qg][ug][i]);
      float s = 0.f;
#pragma unroll
      for (int qg = 0; qg < 4; ++qg)
#pragma unroll
        for (int i = 0; i < 4; ++i) {
          const float x = lg[qg][ug][i];
          const float p = x * __expf(x);
          lg[qg][ug][i] = p;
          s += fabsf(p);
        }
      m = fmaxf(m, __shfl_xor(m, 16));
      m = fmaxf(m, __shfl_xor(m, 32));
      s += __shfl_xor(s, 16);
      s += __shfl_xor(s, 32);
      Mv[ug] = m; Sv[ug] = s;
    }
    if (l4 == 0) {
      atomicMax(&statM[ss * 32 + l15],      encM(Mv[0]));
      atomicMax(&statM[ss * 32 + 16 + l15], encM(Mv[1]));
      atomicAdd(&statS[ss * 32 + l15],      Sv[0]);
      atomicAdd(&statS[ss * 32 + 16 + l15], Sv[1]);
    }
    __syncthreads();

    // per-lane g + apply
#pragma unroll
    for (int ug = 0; ug < 2; ++ug) {
      const int ui = ug * 16 + l15;
      const float M = decM(statM[ss * 32 + ui]);
      const float S = statS[ss * 32 + ui];
      const float em = __expf(-M);
      const float g = vpS[kk * 33 + ui] * em / fmaf(S, em, 1.0f);
#pragma unroll
      for (int qg = 0; qg < 4; ++qg)
#pragma unroll
        for (int i = 0; i < 4; ++i)
          acc[qg][ug][i] = fmaf(g, lg[qg][ug][i], acc[qg][ug][i]);
    }
    // reset slot (kk+2)%3 (next used at kk+2; barrier(kk+1) separates)
    const int rs = (kk + 2) % 3;
    if (tid < 32) { statM[rs * 32 + tid] = 0u; statS[rs * 32 + tid] = 0.f; }
  }

#pragma unroll
  for (int qg = 0; qg < 4; ++qg)
#pragma unroll
    for (int ug = 0; ug < 2; ++ug)
#pragma unroll
      for (int i = 0; i < 4; ++i)
        atomicAdd(&vsum[(size_t)(b * 512 + w * 64 + qg * 16 + l4 * 4 + i) * 256 +
                        u0 + ug * 16 + l15],
                  acc[qg][ug][i]);
}

extern "C" void kernel_launch(void* const* d_in, const int* in_sizes, int n_in,
                              void* d_out, int out_size, void* d_ws, size_t ws_size,
                              hipStream_t stream) {
  const float* query = (const float*)d_in[0];
  const float* key   = (const float*)d_in[1];
  const float* value = (const float*)d_in[2];
  const float* Wk    = (const float*)d_in[3];
  const float* Wq    = (const float*)d_in[4];
  const float* Wva   = (const float*)d_in[5];
  const float* Wal   = (const float*)d_in[6];
  const float* Wvo   = (const float*)d_in[7];
  float* ws = (float*)d_ws;

  float* kproj = ws;                        // 262144 f32
  float* vproj = kproj + 262144;
  float* vsum  = vproj + 262144;
  short* qpF   = (short*)(vsum + 262144);   // 262144 bf16, A-frag-major
  short* WalF  = qpF + 262144;              // 65536 bf16, frag-major
  float* out   = (float*)d_out;

  proj3<<<dim3(16, 4, 4), 256, 0, stream>>>(key, value, query, Wk, Wq, Wva, Wal,
                                            kproj, vproj, qpF, WalF, vsum);
  kernelC<<<dim3(16, 8, 2), 512, 0, stream>>>(qpF, kproj, vproj, WalF, vsum);
  gemm_out<<<dim3(16, 4), 256, 0, stream>>>(vsum, Wvo, out);
}